// Round 7
// baseline (1980.253 us; speedup 1.0000x reference)
//
#include <hip/hip_runtime.h>

#define HH 512
#define WW 512
#define BB 32
#define NIMG (HH * WW)
#define NT (BB * NIMG)
#define TOLF 0.0002f
#define HS 32                 // strip height (output rows per quad block)
#define NSTRIP (HH / HS)      // 16 strips per image
#define TRP 16                // rollA tile rows
#define TIP (TRP + 2)
#define NTBP (HH / TRP)       // 32 rollA tiles per image

// ---------------- cold-path helpers (unchanged structure) ----------------

__device__ __forceinline__ void gs_math(
    const float4& cu, const float4& uu, const float4& ud, float ul, float ur,
    const float4& cv, const float4& vu, const float4& vd, float vl, float vr,
    float Du, float Dv, float F, float Fk, float4& un, float4& vn)
{
    float4 lu, lv;
    lu.x = ul   + cu.y + uu.x + ud.x - 4.f * cu.x;
    lu.y = cu.x + cu.z + uu.y + ud.y - 4.f * cu.y;
    lu.z = cu.y + cu.w + uu.z + ud.z - 4.f * cu.z;
    lu.w = cu.z + ur   + uu.w + ud.w - 4.f * cu.w;
    lv.x = vl   + cv.y + vu.x + vd.x - 4.f * cv.x;
    lv.y = cv.x + cv.z + vu.y + vd.y - 4.f * cv.y;
    lv.z = cv.y + cv.w + vu.z + vd.z - 4.f * cv.z;
    lv.w = cv.z + vr   + vu.w + vd.w - 4.f * cv.w;
    float uvv;
    uvv  = cu.x * cv.x * cv.x;
    un.x = cu.x + (Du * lu.x - uvv + F * (1.f - cu.x));
    vn.x = cv.x + (Dv * lv.x + uvv - Fk * cv.x);
    uvv  = cu.y * cv.y * cv.y;
    un.y = cu.y + (Du * lu.y - uvv + F * (1.f - cu.y));
    vn.y = cv.y + (Dv * lv.y + uvv - Fk * cv.y);
    uvv  = cu.z * cv.z * cv.z;
    un.z = cu.z + (Du * lu.z - uvv + F * (1.f - cu.z));
    vn.z = cv.z + (Dv * lv.z + uvv - Fk * cv.z);
    uvv  = cu.w * cv.w * cv.w;
    un.w = cu.w + (Du * lu.w - uvv + F * (1.f - cu.w));
    vn.w = cv.w + (Dv * lv.w + uvv - Fk * cv.w);
}

__device__ __forceinline__ void load_row(const float* __restrict__ s,
                                         int base, int baseUp, int baseDn, int c0,
                                         float4& c, float4& up, float4& dn, float& l, float& r)
{
    c  = *(const float4*)(s + base   + c0);
    up = *(const float4*)(s + baseUp + c0);
    dn = *(const float4*)(s + baseDn + c0);
    l  = s[base + ((c0 - 1) & (WW - 1))];
    r  = s[base + ((c0 + 4) & (WW - 1))];
}

// ---------------- hot kernel: 4 fused steps, streaming scalar columns ----------------
// 512 threads = 512 columns. Input window in registers (3 rows), levels A,B,C in
// 4-row LDS rings with lag-2 scheduling -> one barrier per row-iteration.
// Ping-pong: parity 0 = ws, 1 = out. steady=1: per-strip max|delta| of all 4 steps.
__global__ __launch_bounds__(512)
void gs_quad(const float* __restrict__ fsU, const float* __restrict__ fsV,
             float* wsU, float* wsV, float* outU, float* outV,
             const float* __restrict__ consts,
             const int* __restrict__ conv, const int* __restrict__ par,
             float* __restrict__ pmax, int tpar, int steady)
{
    __shared__ float Au[4][WW], Av[4][WW], Bu[4][WW], Bv[4][WW], Cu[4][WW], Cv[4][WW];
    __shared__ float eLu[8][4], eLv[8][4], eRu[8][4], eRv[8][4];  // input-row wave-edge ring
    __shared__ float sred[8][4];

    const int b = blockIdx.y;
    if (steady && conv[b]) return;
    const int p = par[b] ^ tpar;
    const float* __restrict__ su = p ? outU : wsU;
    const float* __restrict__ sv = p ? outV : wsV;
    float* __restrict__ dU = p ? wsU : outU;
    float* __restrict__ dV = p ? wsV : outV;
    if (fsU) { su = fsU; sv = fsV; }

    const float Du = consts[0], Dv = consts[1], F = consts[2], Fk = consts[3];
    const int t    = threadIdx.x;          // column 0..511
    const int lane = t & 63, w = t >> 6;   // 8 waves
    const int R0   = blockIdx.x * HS;
    const size_t ib = (size_t)b * NIMG;

    // input register window: rows a-1, a, a+1 (a = j-6)
    float w0u = 0.f, w1u = 0.f, w2u = 0.f, w0v = 0.f, w1v = 0.f, w2v = 0.f;
    float d1 = 0.f, d2 = 0.f, d3 = 0.f, d4 = 0.f;

    // produce one row of level T from level S (both LDS rings), r = target row
    auto prod = [&](const float (&Su)[4][WW], const float (&Sv)[4][WW],
                    float (&Tu)[4][WW], float (&Tv)[4][WW],
                    int r, float& dm, bool acc) {
        const int s0 = r & 3, sm = (r - 1) & 3, sp = (r + 1) & 3;
        const float cu_ = Su[s0][t], uu_ = Su[sm][t], ud_ = Su[sp][t];
        const float cv_ = Sv[s0][t], vu_ = Sv[sm][t], vd_ = Sv[sp][t];
        float ul = __shfl_up(cu_, 1),  vl = __shfl_up(cv_, 1);
        float ur = __shfl_down(cu_, 1), vr = __shfl_down(cv_, 1);
        if (lane == 0)  { ul = Su[s0][(t - 1) & (WW - 1)]; vl = Sv[s0][(t - 1) & (WW - 1)]; }
        if (lane == 63) { ur = Su[s0][(t + 1) & (WW - 1)]; vr = Sv[s0][(t + 1) & (WW - 1)]; }
        const float lu = ul + ur + uu_ + ud_ - 4.f * cu_;
        const float lv = vl + vr + vu_ + vd_ - 4.f * cv_;
        const float uvv = cu_ * cv_ * cv_;
        const float un = cu_ + (Du * lu - uvv + F * (1.f - cu_));
        const float vn = cv_ + (Dv * lv + uvv - Fk * cv_);
        Tu[s0][t] = un; Tv[s0][t] = vn;
        if (acc) dm = fmaxf(dm, fmaxf(fabsf(un - cu_), fabsf(vn - cv_)));
    };

    for (int j = 0; j < 44; ++j) {
        // issue next input row load (row j-4), consumed at window shift below
        float nu = 0.f, nv = 0.f;
        const bool doLoad = (j <= 39);
        if (doLoad) {
            const int g = (R0 + j - 4) & (HH - 1);
            nu = su[ib + (size_t)g * WW + t];
            nv = sv[ib + (size_t)g * WW + t];
        }

        // A[a], a = j-6, from register input window
        if (j >= 3 && j <= 40) {
            const int a = j - 6;
            float ul = __shfl_up(w1u, 1),  vl = __shfl_up(w1v, 1);
            float ur = __shfl_down(w1u, 1), vr = __shfl_down(w1v, 1);
            if (lane == 0)  { ul = eLu[(w + 7) & 7][a & 3]; vl = eLv[(w + 7) & 7][a & 3]; }
            if (lane == 63) { ur = eRu[(w + 1) & 7][a & 3]; vr = eRv[(w + 1) & 7][a & 3]; }
            const float lu = ul + ur + w0u + w2u - 4.f * w1u;
            const float lv = vl + vr + w0v + w2v - 4.f * w1v;
            const float uvv = w1u * w1v * w1v;
            const float un = w1u + (Du * lu - uvv + F * (1.f - w1u));
            const float vn = w1v + (Dv * lv + uvv - Fk * w1v);
            Au[a & 3][t] = un; Av[a & 3][t] = vn;
            if (steady && a >= 0 && a < HS)
                d1 = fmaxf(d1, fmaxf(fabsf(un - w1u), fabsf(vn - w1v)));
        }
        // B[j-8] from A, C[j-10] from B
        if (j >= 6 && j <= 41) prod(Au, Av, Bu, Bv, j - 8,  d2, steady && (j - 8)  >= 0 && (j - 8)  < HS);
        if (j >= 9 && j <= 42) prod(Bu, Bv, Cu, Cv, j - 10, d3, steady && (j - 10) >= 0 && (j - 10) < HS);
        // OUT[o], o = j-12, from C -> global
        if (j >= 12) {
            const int o = j - 12;
            const int s0 = o & 3, sm = (o - 1) & 3, sp = (o + 1) & 3;
            const float cu_ = Cu[s0][t], uu_ = Cu[sm][t], ud_ = Cu[sp][t];
            const float cv_ = Cv[s0][t], vu_ = Cv[sm][t], vd_ = Cv[sp][t];
            float ul = __shfl_up(cu_, 1),  vl = __shfl_up(cv_, 1);
            float ur = __shfl_down(cu_, 1), vr = __shfl_down(cv_, 1);
            if (lane == 0)  { ul = Cu[s0][(t - 1) & (WW - 1)]; vl = Cv[s0][(t - 1) & (WW - 1)]; }
            if (lane == 63) { ur = Cu[s0][(t + 1) & (WW - 1)]; vr = Cv[s0][(t + 1) & (WW - 1)]; }
            const float lu = ul + ur + uu_ + ud_ - 4.f * cu_;
            const float lv = vl + vr + vu_ + vd_ - 4.f * cv_;
            const float uvv = cu_ * cv_ * cv_;
            const float un = cu_ + (Du * lu - uvv + F * (1.f - cu_));
            const float vn = cv_ + (Dv * lv + uvv - Fk * cv_);
            dU[ib + (size_t)(R0 + o) * WW + t] = un;
            dV[ib + (size_t)(R0 + o) * WW + t] = vn;
            if (steady) d4 = fmaxf(d4, fmaxf(fabsf(un - cu_), fabsf(vn - cv_)));
        }

        // window shift + input edge publication (row j-4)
        if (doLoad) {
            const int sl = (j - 4) & 3;
            if (lane == 63) { eLu[w][sl] = nu; eLv[w][sl] = nv; }
            if (lane == 0)  { eRu[w][sl] = nu; eRv[w][sl] = nv; }
        }
        w0u = w1u; w1u = w2u; w2u = nu;
        w0v = w1v; w1v = w2v; w2v = nv;
        __syncthreads();
    }

    if (steady) {
        #pragma unroll
        for (int off = 1; off < 64; off <<= 1) {
            d1 = fmaxf(d1, __shfl_xor(d1, off));
            d2 = fmaxf(d2, __shfl_xor(d2, off));
            d3 = fmaxf(d3, __shfl_xor(d3, off));
            d4 = fmaxf(d4, __shfl_xor(d4, off));
        }
        if (lane == 0) { sred[w][0] = d1; sred[w][1] = d2; sred[w][2] = d3; sred[w][3] = d4; }
        __syncthreads();
        if (t == 0) {
            float m0 = 0.f, m1 = 0.f, m2 = 0.f, m3 = 0.f;
            #pragma unroll
            for (int w2_ = 0; w2_ < 8; ++w2_) {
                m0 = fmaxf(m0, sred[w2_][0]);
                m1 = fmaxf(m1, sred[w2_][1]);
                m2 = fmaxf(m2, sred[w2_][2]);
                m3 = fmaxf(m3, sred[w2_][3]);
            }
            const int idx = b * NSTRIP + blockIdx.x;
            pmax[0 * BB * NSTRIP + idx] = m0;
            pmax[1 * BB * NSTRIP + idx] = m1;
            pmax[2 * BB * NSTRIP + idx] = m2;
            pmax[3 * BB * NSTRIP + idx] = m3;
        }
    }
}

// Reduce per-strip deltas, find first converged step j (1..4), set new conv/par,
// and request rollback (rbJ=j for j<4). j==3 leaves the final state at parity pO.
__global__ void gs_upd(const int* __restrict__ convO, const int* __restrict__ parO,
                       int* convN, int* parN, int* rbJ,
                       const float* __restrict__ pmax)
{
    const int b = blockIdx.x, t = threadIdx.x;
    if (convO[b]) { if (t == 0) { convN[b] = 1; parN[b] = parO[b]; rbJ[b] = 0; } return; }
    float v0 = 0.f, v1 = 0.f, v2 = 0.f, v3 = 0.f;
    if (t < NSTRIP) {
        const int idx = b * NSTRIP + t;
        v0 = pmax[0 * BB * NSTRIP + idx];
        v1 = pmax[1 * BB * NSTRIP + idx];
        v2 = pmax[2 * BB * NSTRIP + idx];
        v3 = pmax[3 * BB * NSTRIP + idx];
    }
    #pragma unroll
    for (int off = 1; off < NSTRIP; off <<= 1) {
        v0 = fmaxf(v0, __shfl_xor(v0, off));
        v1 = fmaxf(v1, __shfl_xor(v1, off));
        v2 = fmaxf(v2, __shfl_xor(v2, off));
        v3 = fmaxf(v3, __shfl_xor(v3, off));
    }
    if (t == 0) {
        int j = 0;
        if      (v0 < TOLF) j = 1;
        else if (v1 < TOLF) j = 2;
        else if (v2 < TOLF) j = 3;
        else if (v3 < TOLF) j = 4;
        const int pO = parO[b];
        convN[b] = (j != 0);
        parN[b]  = (j == 3) ? pO : (pO ^ 1);
        rbJ[b]   = (j >= 1 && j <= 3) ? j : 0;
    }
}

// Cold rollback part A: redo the first 2 steps (tile-fused) when rbJ >= 2.
__global__ __launch_bounds__(256)
void gs_rollA(const float* __restrict__ fsU, const float* __restrict__ fsV,
              float* wsU, float* wsV, float* outU, float* outV,
              const float* __restrict__ consts,
              const int* __restrict__ parO, const int* __restrict__ rbJ)
{
    __shared__ float iu[TIP][WW];
    __shared__ float iv[TIP][WW];
    const int b = blockIdx.y;
    if (rbJ[b] < 2) return;
    const int p = parO[b];
    const float* __restrict__ su = p ? outU : wsU;
    const float* __restrict__ sv = p ? outV : wsV;
    float* __restrict__ dU = p ? wsU : outU;
    float* __restrict__ dV = p ? wsV : outV;
    if (fsU) { su = fsU; sv = fsV; }
    const float Du = consts[0], Dv = consts[1], F = consts[2], Fk = consts[3];
    const int t = threadIdx.x, c0 = (t & 127) * 4, rw = t >> 7;
    const int r0 = blockIdx.x * TRP;
    for (int i = 0; i < TIP; i += 2) {
        const int li = i + rw;
        const int h  = (r0 - 1 + li) & (HH - 1);
        const int hm = (h - 1) & (HH - 1);
        const int hp = (h + 1) & (HH - 1);
        const int base   = b * NIMG + h  * WW;
        const int baseUp = b * NIMG + hm * WW;
        const int baseDn = b * NIMG + hp * WW;
        float4 cu, uu, ud, cv, vu, vd; float ul, ur, vl, vr;
        load_row(su, base, baseUp, baseDn, c0, cu, uu, ud, ul, ur);
        load_row(sv, base, baseUp, baseDn, c0, cv, vu, vd, vl, vr);
        float4 un, vn;
        gs_math(cu, uu, ud, ul, ur, cv, vu, vd, vl, vr, Du, Dv, F, Fk, un, vn);
        *(float4*)(&iu[li][c0]) = un;
        *(float4*)(&iv[li][c0]) = vn;
    }
    __syncthreads();
    for (int i = 0; i < TRP; i += 2) {
        const int li = 1 + i + rw;
        const int h  = r0 + i + rw;
        float4 cu = *(const float4*)(&iu[li][c0]);
        float4 uu = *(const float4*)(&iu[li - 1][c0]);
        float4 ud = *(const float4*)(&iu[li + 1][c0]);
        const float ul = iu[li][(c0 - 1) & (WW - 1)];
        const float ur = iu[li][(c0 + 4) & (WW - 1)];
        float4 cv = *(const float4*)(&iv[li][c0]);
        float4 vu = *(const float4*)(&iv[li - 1][c0]);
        float4 vd = *(const float4*)(&iv[li + 1][c0]);
        const float vl = iv[li][(c0 - 1) & (WW - 1)];
        const float vr = iv[li][(c0 + 4) & (WW - 1)];
        float4 un, vn;
        gs_math(cu, uu, ud, ul, ur, cv, vu, vd, vl, vr, Du, Dv, F, Fk, un, vn);
        *(float4*)(dU + b * NIMG + h * WW + c0) = un;
        *(float4*)(dV + b * NIMG + h * WW + c0) = vn;
    }
}

// Cold rollback part B: one single step. rbJ==1: from original source (pO);
// rbJ==3: from rollA's 2-step state (!pO) back into pO.
__global__ __launch_bounds__(256)
void gs_rollB(const float* __restrict__ fsU, const float* __restrict__ fsV,
              float* wsU, float* wsV, float* outU, float* outV,
              const float* __restrict__ consts,
              const int* __restrict__ parO, const int* __restrict__ rbJ)
{
    const int b = blockIdx.y;
    const int j = rbJ[b];
    if (j != 1 && j != 3) return;
    const int q = parO[b] ^ (j == 3 ? 1 : 0);
    const float* __restrict__ su = q ? outU : wsU;
    const float* __restrict__ sv = q ? outV : wsV;
    float* __restrict__ dU = q ? wsU : outU;
    float* __restrict__ dV = q ? wsV : outV;
    if (j == 1 && fsU) { su = fsU; sv = fsV; }
    const float Du = consts[0], Dv = consts[1], F = consts[2], Fk = consts[3];
    const int idx = blockIdx.x * 256 + threadIdx.x;
    const int h  = idx >> 7;
    const int c0 = (idx & 127) * 4;
    const int hm = (h - 1) & (HH - 1);
    const int hp = (h + 1) & (HH - 1);
    const int base   = b * NIMG + h  * WW;
    const int baseUp = b * NIMG + hm * WW;
    const int baseDn = b * NIMG + hp * WW;
    float4 cu, uu, ud, cv, vu, vd; float ul, ur, vl, vr;
    load_row(su, base, baseUp, baseDn, c0, cu, uu, ud, ul, ur);
    load_row(sv, base, baseUp, baseDn, c0, cv, vu, vd, vl, vr);
    float4 un, vn;
    gs_math(cu, uu, ud, ul, ur, cv, vu, vd, vl, vr, Du, Dv, F, Fk, un, vn);
    *(float4*)(dU + base + c0) = un;
    *(float4*)(dV + base + c0) = vn;
}

__global__ void gs_init(const float* lDu, const float* lDv, const float* rF, const float* rk,
                        float* consts, int* conv0, int* par0, int* rbJ)
{
    const int t = threadIdx.x;
    if (t == 0) {
        const float a = lDu[0], c = lDv[0];
        const float Du = (a > 0.f) ? a + log1pf(expf(-a)) : log1pf(expf(a));
        const float Dv = (c > 0.f) ? c + log1pf(expf(-c)) : log1pf(expf(c));
        const float F  = 0.1f / (1.f + expf(-rF[0]));
        const float kk = 0.1f / (1.f + expf(-rk[0]));
        consts[0] = Du; consts[1] = Dv; consts[2] = F; consts[3] = F + kk;
    }
    if (t < BB) { conv0[t] = 0; par0[t] = 0; rbJ[t] = 0; }
}

// Batches whose final parity is 0 live in ws — move them to d_out.
__launch_bounds__(256)
__global__ void gs_final(const float* __restrict__ wsU, const float* __restrict__ wsV,
                         float* outU, float* outV, const int* __restrict__ par)
{
    const int b = blockIdx.y;
    if (par[b] != 0) return;  // already in d_out
    const int off = b * NIMG + (blockIdx.x * 256 + threadIdx.x) * 4;
    *(float4*)(outU + off) = *(const float4*)(wsU + off);
    *(float4*)(outV + off) = *(const float4*)(wsV + off);
}

extern "C" void kernel_launch(void* const* d_in, const int* in_sizes, int n_in,
                              void* d_out, int out_size, void* d_ws, size_t ws_size,
                              hipStream_t stream)
{
    const float* in_u = (const float*)d_in[0];
    const float* in_v = (const float*)d_in[1];
    const float* lDu  = (const float*)d_in[2];
    const float* lDv  = (const float*)d_in[3];
    const float* rF   = (const float*)d_in[4];
    const float* rk   = (const float*)d_in[5];
    const int NQUAD_STEADY = 16;  // max_steps=64 -> 16 quads
    const int NQUAD_BPTT   = 8;   // K=32 -> 8 quads

    float* wsU = (float*)d_ws;
    float* wsV = wsU + NT;
    float* aux = wsV + NT;
    float* consts = aux;                    // 4 floats
    int* conv0 = (int*)(aux + 4);           // 32
    int* par0  = conv0 + BB;                // 32
    int* conv1 = par0 + BB;                 // 32
    int* par1  = conv1 + BB;                // 32
    int* rbJ   = par1 + BB;                 // 32
    float* pmax = (float*)(rbJ + BB);       // 4 * 32 * 16

    float* outU = (float*)d_out;
    float* outV = outU + NT;

    gs_init<<<1, 64, 0, stream>>>(lDu, lDv, rF, rk, consts, conv0, par0, rbJ);

    const dim3 gridQ(NSTRIP, BB);
    for (int s = 0; s < NQUAD_STEADY; ++s) {
        int* cO = (s & 1) ? conv1 : conv0;
        int* pO = (s & 1) ? par1  : par0;
        int* cN = (s & 1) ? conv0 : conv1;
        int* pN = (s & 1) ? par0  : par1;
        const float* fU = (s == 0) ? in_u : nullptr;
        const float* fV = (s == 0) ? in_v : nullptr;
        gs_quad<<<gridQ, 512, 0, stream>>>(fU, fV, wsU, wsV, outU, outV, consts,
                                           cO, pO, pmax, 0, 1);
        gs_upd<<<BB, 64, 0, stream>>>(cO, pO, cN, pN, rbJ, pmax);
        gs_rollA<<<dim3(NTBP, BB), 256, 0, stream>>>(fU, fV, wsU, wsV, outU, outV,
                                                     consts, pO, rbJ);
        gs_rollB<<<dim3(NIMG / 1024, BB), 256, 0, stream>>>(fU, fV, wsU, wsV, outU, outV,
                                                            consts, pO, rbJ);
    }
    // after 16 quads the live state arrays are index 0 (conv0/par0)
    for (int j = 0; j < NQUAD_BPTT; ++j) {
        gs_quad<<<gridQ, 512, 0, stream>>>(nullptr, nullptr, wsU, wsV, outU, outV, consts,
                                           conv0, par0, pmax, j & 1, 0);
    }
    gs_final<<<dim3(NIMG / 1024, BB), 256, 0, stream>>>(wsU, wsV, outU, outV, par0);
}

// Round 9
// 1308.561 us; speedup vs baseline: 1.5133x; 1.5133x over previous
//
#include <hip/hip_runtime.h>

#define HH 512
#define WW 512
#define BB 32
#define NIMG (HH * WW)
#define NT (BB * NIMG)
#define TOLF 0.0002f
#define HS 32                 // strip height (output rows per quad block)
#define NSTRIP (HH / HS)      // 16 strips per image
#define TRP 16                // rollA tile rows
#define TIP (TRP + 2)
#define NTBP (HH / TRP)       // 32 rollA tiles per image

__device__ __forceinline__ void gs_math(
    const float4& cu, const float4& uu, const float4& ud, float ul, float ur,
    const float4& cv, const float4& vu, const float4& vd, float vl, float vr,
    float Du, float Dv, float F, float Fk, float4& un, float4& vn)
{
    float4 lu, lv;
    lu.x = ul   + cu.y + uu.x + ud.x - 4.f * cu.x;
    lu.y = cu.x + cu.z + uu.y + ud.y - 4.f * cu.y;
    lu.z = cu.y + cu.w + uu.z + ud.z - 4.f * cu.z;
    lu.w = cu.z + ur   + uu.w + ud.w - 4.f * cu.w;
    lv.x = vl   + cv.y + vu.x + vd.x - 4.f * cv.x;
    lv.y = cv.x + cv.z + vu.y + vd.y - 4.f * cv.y;
    lv.z = cv.y + cv.w + vu.z + vd.z - 4.f * cv.z;
    lv.w = cv.z + vr   + vu.w + vd.w - 4.f * cv.w;
    float uvv;
    uvv  = cu.x * cv.x * cv.x;
    un.x = cu.x + (Du * lu.x - uvv + F * (1.f - cu.x));
    vn.x = cv.x + (Dv * lv.x + uvv - Fk * cv.x);
    uvv  = cu.y * cv.y * cv.y;
    un.y = cu.y + (Du * lu.y - uvv + F * (1.f - cu.y));
    vn.y = cv.y + (Dv * lv.y + uvv - Fk * cv.y);
    uvv  = cu.z * cv.z * cv.z;
    un.z = cu.z + (Du * lu.z - uvv + F * (1.f - cu.z));
    vn.z = cv.z + (Dv * lv.z + uvv - Fk * cv.z);
    uvv  = cu.w * cv.w * cv.w;
    un.w = cu.w + (Du * lu.w - uvv + F * (1.f - cu.w));
    vn.w = cv.w + (Dv * lv.w + uvv - Fk * cv.w);
}

__device__ __forceinline__ void load_row(const float* __restrict__ s,
                                         int base, int baseUp, int baseDn, int c0,
                                         float4& c, float4& up, float4& dn, float& l, float& r)
{
    c  = *(const float4*)(s + base   + c0);
    up = *(const float4*)(s + baseUp + c0);
    dn = *(const float4*)(s + baseDn + c0);
    l  = s[base + ((c0 - 1) & (WW - 1))];
    r  = s[base + ((c0 + 4) & (WW - 1))];
}

__device__ __forceinline__ float dmax8(const float4& un, const float4& cu,
                                       const float4& vn, const float4& cv)
{
    return fmaxf(
        fmaxf(fmaxf(fabsf(un.x - cu.x), fabsf(un.y - cu.y)),
              fmaxf(fabsf(un.z - cu.z), fabsf(un.w - cu.w))),
        fmaxf(fmaxf(fabsf(vn.x - cv.x), fabsf(vn.y - cv.y)),
              fmaxf(fabsf(vn.z - cv.z), fabsf(vn.w - cv.w))));
}

// ---------------- hot kernel: 4 fused steps, wave-specialized pipeline ----------------
// 512 threads = 4 groups (A,B,C,OUT) x 128 float4-lanes. Each group produces one row
// per iteration of its level: vertical neighbors from a 3-row register window,
// new row read from the previous level's 4-row LDS ring, horizontal edges via shfl.
// Lags 6/9/12/15: at iteration j, level L writes ring row (j-6-3L); its consumer
// reads ring row (j-7-3L) (written last iter, slot differs by 1) and edge scalars of
// row (j-9-3L) (slot differs by 3); the write recycles row (j-10-3L), whose last
// reader finished at iteration j-1. One barrier per iteration, race-free.
__global__ __launch_bounds__(512)
void gs_quad(const float* __restrict__ fsU, const float* __restrict__ fsV,
             float* wsU, float* wsV, float* outU, float* outV,
             const float* __restrict__ consts,
             const int* __restrict__ conv, const int* __restrict__ par,
             float* __restrict__ pmax, int tpar, int steady)
{
    __shared__ float ring[3][2][4][WW];   // [level A/B/C][u,v][slot][col] = 48 KB
    __shared__ float sred[8];

    const int b = blockIdx.y;
    if (steady && conv[b]) return;
    const int p = par[b] ^ tpar;
    const float* __restrict__ su = p ? outU : wsU;
    const float* __restrict__ sv = p ? outV : wsV;
    float* __restrict__ dU = p ? wsU : outU;
    float* __restrict__ dV = p ? wsV : outV;
    if (fsU) { su = fsU; sv = fsV; }

    const float Du = consts[0], Dv = consts[1], F = consts[2], Fk = consts[3];
    const int t = threadIdx.x;
    const int g = t >> 7;              // group: 0=A,1=B,2=C,3=OUT
    const int gt = t & 127;            // lane within group (float4 column)
    const int lane = t & 63;
    const int c0 = gt * 4;
    const int R0 = blockIdx.x * HS;
    const size_t ib = (size_t)b * NIMG;

    const int readStart = 4 * g;          // A:0 B:4 C:8 O:12
    const int readEnd   = 39 + 2 * g;     // A:39 B:41 C:43 O:45
    float4 m0u = {0,0,0,0}, m1u = {0,0,0,0}, m2u = {0,0,0,0};
    float4 m0v = {0,0,0,0}, m1v = {0,0,0,0}, m2v = {0,0,0,0};
    float dm = 0.f;

    for (int j = 0; j <= 46; ++j) {
        // ---- read new window row (row rp+2 of my source level) ----
        float4 nu = {0,0,0,0}, nv = {0,0,0,0};
        if (j >= readStart && j <= readEnd) {
            const int rr = j - 4 - 3 * g;
            if (g == 0) {
                const int gr = (R0 + rr) & (HH - 1);
                nu = *(const float4*)(su + ib + (size_t)gr * WW + c0);
                nv = *(const float4*)(sv + ib + (size_t)gr * WW + c0);
            } else {
                const int s = rr & 3;
                nu = *(const float4*)&ring[g - 1][0][s][c0];
                nv = *(const float4*)&ring[g - 1][1][s][c0];
            }
        }

        // ---- produce row rp of my level from register window ----
        if (j >= readStart + 3 && j <= readEnd + 1) {
            const int rp = j - 6 - 3 * g;
            float ul = __shfl_up(m1u.w, 1),   vl = __shfl_up(m1v.w, 1);
            float ur = __shfl_down(m1u.x, 1), vr = __shfl_down(m1v.x, 1);
            if (lane == 0 || lane == 63) {
                if (g == 0) {
                    const int gr = (R0 + rp) & (HH - 1);
                    const size_t rb = ib + (size_t)gr * WW;
                    if (lane == 0) { ul = su[rb + ((c0 - 1) & (WW - 1))];
                                     vl = sv[rb + ((c0 - 1) & (WW - 1))]; }
                    else           { ur = su[rb + ((c0 + 4) & (WW - 1))];
                                     vr = sv[rb + ((c0 + 4) & (WW - 1))]; }
                } else {
                    const int s = rp & 3;
                    if (lane == 0) { ul = ring[g - 1][0][s][(c0 - 1) & (WW - 1)];
                                     vl = ring[g - 1][1][s][(c0 - 1) & (WW - 1)]; }
                    else           { ur = ring[g - 1][0][s][(c0 + 4) & (WW - 1)];
                                     vr = ring[g - 1][1][s][(c0 + 4) & (WW - 1)]; }
                }
            }
            float4 un, vn;
            gs_math(m1u, m0u, m2u, ul, ur, m1v, m0v, m2v, vl, vr, Du, Dv, F, Fk, un, vn);
            if (g == 3) {
                *(float4*)(dU + ib + (size_t)(R0 + rp) * WW + c0) = un;
                *(float4*)(dV + ib + (size_t)(R0 + rp) * WW + c0) = vn;
            } else {
                const int s = rp & 3;
                *(float4*)&ring[g][0][s][c0] = un;
                *(float4*)&ring[g][1][s][c0] = vn;
            }
            if (steady && rp >= 0 && rp < HS)
                dm = fmaxf(dm, dmax8(un, m1u, vn, m1v));
        }

        // ---- shift window ----
        m0u = m1u; m1u = m2u; m2u = nu;
        m0v = m1v; m1v = m2v; m2v = nv;
        __syncthreads();
    }

    if (steady) {
        #pragma unroll
        for (int off = 1; off < 64; off <<= 1)
            dm = fmaxf(dm, __shfl_xor(dm, off));
        const int w = t >> 6;
        if (lane == 0) sred[w] = dm;
        __syncthreads();
        if (gt == 0) {
            const int idx = b * NSTRIP + blockIdx.x;
            pmax[g * BB * NSTRIP + idx] = fmaxf(sred[2 * g], sred[2 * g + 1]);
        }
    }
}

// Reduce per-strip deltas, find first converged step j (1..4), set new conv/par,
// and request rollback (rbJ=j for j<4). j==3 leaves the final state at parity pO.
__global__ void gs_upd(const int* __restrict__ convO, const int* __restrict__ parO,
                       int* convN, int* parN, int* rbJ,
                       const float* __restrict__ pmax)
{
    const int b = blockIdx.x, t = threadIdx.x;
    if (convO[b]) { if (t == 0) { convN[b] = 1; parN[b] = parO[b]; rbJ[b] = 0; } return; }
    float v0 = 0.f, v1 = 0.f, v2 = 0.f, v3 = 0.f;
    if (t < NSTRIP) {
        const int idx = b * NSTRIP + t;
        v0 = pmax[0 * BB * NSTRIP + idx];
        v1 = pmax[1 * BB * NSTRIP + idx];
        v2 = pmax[2 * BB * NSTRIP + idx];
        v3 = pmax[3 * BB * NSTRIP + idx];
    }
    #pragma unroll
    for (int off = 1; off < NSTRIP; off <<= 1) {
        v0 = fmaxf(v0, __shfl_xor(v0, off));
        v1 = fmaxf(v1, __shfl_xor(v1, off));
        v2 = fmaxf(v2, __shfl_xor(v2, off));
        v3 = fmaxf(v3, __shfl_xor(v3, off));
    }
    if (t == 0) {
        int j = 0;
        if      (v0 < TOLF) j = 1;
        else if (v1 < TOLF) j = 2;
        else if (v2 < TOLF) j = 3;
        else if (v3 < TOLF) j = 4;
        const int pO = parO[b];
        convN[b] = (j != 0);
        parN[b]  = (j == 3) ? pO : (pO ^ 1);
        rbJ[b]   = (j >= 1 && j <= 3) ? j : 0;
    }
}

// Cold rollback part A: redo the first 2 steps (tile-fused) when rbJ >= 2.
__global__ __launch_bounds__(256)
void gs_rollA(const float* __restrict__ fsU, const float* __restrict__ fsV,
              float* wsU, float* wsV, float* outU, float* outV,
              const float* __restrict__ consts,
              const int* __restrict__ parO, const int* __restrict__ rbJ)
{
    __shared__ float iu[TIP][WW];
    __shared__ float iv[TIP][WW];
    const int b = blockIdx.y;
    if (rbJ[b] < 2) return;
    const int p = parO[b];
    const float* __restrict__ su = p ? outU : wsU;
    const float* __restrict__ sv = p ? outV : wsV;
    float* __restrict__ dU = p ? wsU : outU;
    float* __restrict__ dV = p ? wsV : outV;
    if (fsU) { su = fsU; sv = fsV; }
    const float Du = consts[0], Dv = consts[1], F = consts[2], Fk = consts[3];
    const int t = threadIdx.x, c0 = (t & 127) * 4, rw = t >> 7;
    const int r0 = blockIdx.x * TRP;
    for (int i = 0; i < TIP; i += 2) {
        const int li = i + rw;
        const int h  = (r0 - 1 + li) & (HH - 1);
        const int hm = (h - 1) & (HH - 1);
        const int hp = (h + 1) & (HH - 1);
        const int base   = b * NIMG + h  * WW;
        const int baseUp = b * NIMG + hm * WW;
        const int baseDn = b * NIMG + hp * WW;
        float4 cu, uu, ud, cv, vu, vd; float ul, ur, vl, vr;
        load_row(su, base, baseUp, baseDn, c0, cu, uu, ud, ul, ur);
        load_row(sv, base, baseUp, baseDn, c0, cv, vu, vd, vl, vr);
        float4 un, vn;
        gs_math(cu, uu, ud, ul, ur, cv, vu, vd, vl, vr, Du, Dv, F, Fk, un, vn);
        *(float4*)(&iu[li][c0]) = un;
        *(float4*)(&iv[li][c0]) = vn;
    }
    __syncthreads();
    for (int i = 0; i < TRP; i += 2) {
        const int li = 1 + i + rw;
        const int h  = r0 + i + rw;
        float4 cu = *(const float4*)(&iu[li][c0]);
        float4 uu = *(const float4*)(&iu[li - 1][c0]);
        float4 ud = *(const float4*)(&iu[li + 1][c0]);
        const float ul = iu[li][(c0 - 1) & (WW - 1)];
        const float ur = iu[li][(c0 + 4) & (WW - 1)];
        float4 cv = *(const float4*)(&iv[li][c0]);
        float4 vu = *(const float4*)(&iv[li - 1][c0]);
        float4 vd = *(const float4*)(&iv[li + 1][c0]);
        const float vl = iv[li][(c0 - 1) & (WW - 1)];
        const float vr = iv[li][(c0 + 4) & (WW - 1)];
        float4 un, vn;
        gs_math(cu, uu, ud, ul, ur, cv, vu, vd, vl, vr, Du, Dv, F, Fk, un, vn);
        *(float4*)(dU + b * NIMG + h * WW + c0) = un;
        *(float4*)(dV + b * NIMG + h * WW + c0) = vn;
    }
}

// Cold rollback part B: one single step. rbJ==1: from original source (pO);
// rbJ==3: from rollA's 2-step state (!pO) back into pO.
__global__ __launch_bounds__(256)
void gs_rollB(const float* __restrict__ fsU, const float* __restrict__ fsV,
              float* wsU, float* wsV, float* outU, float* outV,
              const float* __restrict__ consts,
              const int* __restrict__ parO, const int* __restrict__ rbJ)
{
    const int b = blockIdx.y;
    const int j = rbJ[b];
    if (j != 1 && j != 3) return;
    const int q = parO[b] ^ (j == 3 ? 1 : 0);
    const float* __restrict__ su = q ? outU : wsU;
    const float* __restrict__ sv = q ? outV : wsV;
    float* __restrict__ dU = q ? wsU : outU;
    float* __restrict__ dV = q ? wsV : outV;
    if (j == 1 && fsU) { su = fsU; sv = fsV; }
    const float Du = consts[0], Dv = consts[1], F = consts[2], Fk = consts[3];
    const int idx = blockIdx.x * 256 + threadIdx.x;
    const int h  = idx >> 7;
    const int c0 = (idx & 127) * 4;
    const int hm = (h - 1) & (HH - 1);
    const int hp = (h + 1) & (HH - 1);
    const int base   = b * NIMG + h  * WW;
    const int baseUp = b * NIMG + hm * WW;
    const int baseDn = b * NIMG + hp * WW;
    float4 cu, uu, ud, cv, vu, vd; float ul, ur, vl, vr;
    load_row(su, base, baseUp, baseDn, c0, cu, uu, ud, ul, ur);
    load_row(sv, base, baseUp, baseDn, c0, cv, vu, vd, vl, vr);
    float4 un, vn;
    gs_math(cu, uu, ud, ul, ur, cv, vu, vd, vl, vr, Du, Dv, F, Fk, un, vn);
    *(float4*)(dU + base + c0) = un;
    *(float4*)(dV + base + c0) = vn;
}

__global__ void gs_init(const float* lDu, const float* lDv, const float* rF, const float* rk,
                        float* consts, int* conv0, int* par0, int* rbJ)
{
    const int t = threadIdx.x;
    if (t == 0) {
        const float a = lDu[0], c = lDv[0];
        const float Du = (a > 0.f) ? a + log1pf(expf(-a)) : log1pf(expf(a));
        const float Dv = (c > 0.f) ? c + log1pf(expf(-c)) : log1pf(expf(c));
        const float F  = 0.1f / (1.f + expf(-rF[0]));
        const float kk = 0.1f / (1.f + expf(-rk[0]));
        consts[0] = Du; consts[1] = Dv; consts[2] = F; consts[3] = F + kk;
    }
    if (t < BB) { conv0[t] = 0; par0[t] = 0; rbJ[t] = 0; }
}

// Batches whose final parity is 0 live in ws — move them to d_out.
__launch_bounds__(256)
__global__ void gs_final(const float* __restrict__ wsU, const float* __restrict__ wsV,
                         float* outU, float* outV, const int* __restrict__ par)
{
    const int b = blockIdx.y;
    if (par[b] != 0) return;  // already in d_out
    const int off = b * NIMG + (blockIdx.x * 256 + threadIdx.x) * 4;
    *(float4*)(outU + off) = *(const float4*)(wsU + off);
    *(float4*)(outV + off) = *(const float4*)(wsV + off);
}

extern "C" void kernel_launch(void* const* d_in, const int* in_sizes, int n_in,
                              void* d_out, int out_size, void* d_ws, size_t ws_size,
                              hipStream_t stream)
{
    const float* in_u = (const float*)d_in[0];
    const float* in_v = (const float*)d_in[1];
    const float* lDu  = (const float*)d_in[2];
    const float* lDv  = (const float*)d_in[3];
    const float* rF   = (const float*)d_in[4];
    const float* rk   = (const float*)d_in[5];
    const int NQUAD_STEADY = 16;  // max_steps=64 -> 16 quads
    const int NQUAD_BPTT   = 8;   // K=32 -> 8 quads

    float* wsU = (float*)d_ws;
    float* wsV = wsU + NT;
    float* aux = wsV + NT;
    float* consts = aux;                    // 4 floats
    int* conv0 = (int*)(aux + 4);           // 32
    int* par0  = conv0 + BB;                // 32
    int* conv1 = par0 + BB;                 // 32
    int* par1  = conv1 + BB;                // 32
    int* rbJ   = par1 + BB;                 // 32
    float* pmax = (float*)(rbJ + BB);       // 4 * 32 * 16

    float* outU = (float*)d_out;
    float* outV = outU + NT;

    gs_init<<<1, 64, 0, stream>>>(lDu, lDv, rF, rk, consts, conv0, par0, rbJ);

    const dim3 gridQ(NSTRIP, BB);
    for (int s = 0; s < NQUAD_STEADY; ++s) {
        int* cO = (s & 1) ? conv1 : conv0;
        int* pO = (s & 1) ? par1  : par0;
        int* cN = (s & 1) ? conv0 : conv1;
        int* pN = (s & 1) ? par0  : par1;
        const float* fU = (s == 0) ? in_u : nullptr;
        const float* fV = (s == 0) ? in_v : nullptr;
        gs_quad<<<gridQ, 512, 0, stream>>>(fU, fV, wsU, wsV, outU, outV, consts,
                                           cO, pO, pmax, 0, 1);
        gs_upd<<<BB, 64, 0, stream>>>(cO, pO, cN, pN, rbJ, pmax);
        gs_rollA<<<dim3(NTBP, BB), 256, 0, stream>>>(fU, fV, wsU, wsV, outU, outV,
                                                     consts, pO, rbJ);
        gs_rollB<<<dim3(NIMG / 1024, BB), 256, 0, stream>>>(fU, fV, wsU, wsV, outU, outV,
                                                            consts, pO, rbJ);
    }
    // after 16 quads the live state arrays are index 0 (conv0/par0)
    for (int j = 0; j < NQUAD_BPTT; ++j) {
        gs_quad<<<gridQ, 512, 0, stream>>>(nullptr, nullptr, wsU, wsV, outU, outV, consts,
                                           conv0, par0, pmax, j & 1, 0);
    }
    gs_final<<<dim3(NIMG / 1024, BB), 256, 0, stream>>>(wsU, wsV, outU, outV, par0);
}